// Round 13
// baseline (303.306 us; speedup 1.0000x reference)
//
#include <hip/hip_runtime.h>
#include <hip/hip_bf16.h>
#include <cstdint>
#include <cstddef>

// BertMoE: B=4,S=2048,H=768,F=3072,E=8,K=2. tokens T=8192, pairs=16384.
#define T_TOK 8192
#define HDIM  768
#define FDIM  3072
#define NEXP  8

typedef __attribute__((ext_vector_type(8))) __bf16 bf16x8;
typedef __attribute__((ext_vector_type(4))) float  f32x4;

static __device__ __forceinline__ f32x4 mfma16(bf16x8 a, bf16x8 b, f32x4 c) {
  return __builtin_amdgcn_mfma_f32_16x16x32_bf16(a, b, c, 0, 0, 0);
}

static __device__ __forceinline__ unsigned short f2b(float f) {
  return __builtin_bit_cast(unsigned short, (__bf16)f);
}

// fast gelu: 0.5x(1+tanh(0.79788456(x+0.044715x^3))), max |err| ~3e-4 (R5/R6-validated)
static __device__ __forceinline__ float gelu_f(float x) {
  float x2 = x * x;
  float y = x * (0.7978845608f + 0.0356774081f * x2);
  float ay = __builtin_fabsf(y);
  float z = __builtin_amdgcn_exp2f(ay * -2.885390082f);   // exp(-2|y|)
  float t = (1.0f - z) * __builtin_amdgcn_rcpf(1.0f + z);
  t = __builtin_copysignf(t, y);
  return 0.5f * x * (1.0f + t);
}

// ---------------- workspace layout (bytes) ----------------
static constexpr size_t OFF_XB   = 0;                                        // T*H bf16
static constexpr size_t OFF_WIB  = OFF_XB  + (size_t)T_TOK * HDIM * 2;       // E*F*H bf16
static constexpr size_t OFF_WOB  = OFF_WIB + (size_t)NEXP * FDIM * HDIM * 2; // E*H*F bf16
static constexpr size_t OFF_HBUF = OFF_WOB + (size_t)NEXP * HDIM * FDIM * 2; // 2T*F bf16
static constexpr size_t OFF_META = OFF_HBUF + (size_t)2 * T_TOK * FDIM * 2;
static constexpr size_t OFF_TOKE = OFF_META + 256;
static constexpr size_t OFF_TOKW = OFF_TOKE + 65536;
static constexpr size_t OFF_PTOK = OFF_TOKW + 65536;
static constexpr size_t OFF_PW   = OFF_PTOK + 65536;
static constexpr size_t OFF_TILE = OFF_PW + 65536;
// OFF_TILE layout: tileA_e[256] | tileA_mt[256] | ntiles[2]  (128-row tiles)
// stage [16384][768] f32 = 50.33 MB: ALIASES xb+wib (dead once gemmA is done)
static constexpr size_t OFF_STAGE = 0;

// ---------------- fp32 -> bf16 convert ----------------
__global__ __launch_bounds__(256) void cvt_kernel(const float* __restrict__ s,
                                                  unsigned short* __restrict__ d, int n4) {
  int i = blockIdx.x * 256 + threadIdx.x;
  int stride = gridDim.x * 256;
  for (; i < n4; i += stride) {
    float4 v = ((const float4*)s)[i];
    ushort4 o;
    o.x = f2b(v.x); o.y = f2b(v.y); o.z = f2b(v.z); o.w = f2b(v.w);
    ((ushort4*)d)[i] = o;
  }
}

// ---------------- router: logits, top2, softmax; also emits xb (bf16 of x) ----------------
__global__ __launch_bounds__(256) void router_kernel(const float* __restrict__ x,
                                                     const float* __restrict__ Wr,
                                                     int* __restrict__ tok_e,
                                                     float* __restrict__ tok_w,
                                                     unsigned short* __restrict__ xb) {
  __shared__ float wr[NEXP * HDIM];
  int tid = threadIdx.x;
  for (int i = tid; i < NEXP * HDIM; i += 256) wr[i] = Wr[i];
  __syncthreads();
  int lane = tid & 63;
  int wv = tid >> 6;
  int t = blockIdx.x * 4 + wv;
  const float* xr = x + (size_t)t * HDIM;
  unsigned short* xbr = xb + (size_t)t * HDIM;
  float p[NEXP];
#pragma unroll
  for (int e = 0; e < NEXP; ++e) p[e] = 0.f;
  for (int j = 0; j < HDIM / 64; ++j) {
    float xv = xr[j * 64 + lane];
    xbr[j * 64 + lane] = f2b(xv);
#pragma unroll
    for (int e = 0; e < NEXP; ++e) p[e] += xv * wr[e * HDIM + j * 64 + lane];
  }
#pragma unroll
  for (int e = 0; e < NEXP; ++e) {
    float v = p[e];
    for (int off = 32; off; off >>= 1) v += __shfl_xor(v, off);
    p[e] = v;
  }
  if (lane == 0) {
    float v0 = -1e30f, v1 = -1e30f; int i0 = 0, i1 = 0;
#pragma unroll
    for (int e = 0; e < NEXP; ++e) {
      float v = p[e];
      if (v > v0) { v1 = v0; i1 = i0; v0 = v; i0 = e; }
      else if (v > v1) { v1 = v; i1 = e; }
    }
    float ew = expf(v1 - v0);
    float w0 = 1.0f / (1.0f + ew);
    float w1 = ew * w0;
    tok_e[t * 2 + 0] = i0; tok_w[t * 2 + 0] = w0;
    tok_e[t * 2 + 1] = i1; tok_w[t * 2 + 1] = w1;
  }
}

// ---------------- count / scan+tiles / scatter ----------------
__global__ __launch_bounds__(256) void count_kernel(const int* __restrict__ tok_e,
                                                    int* __restrict__ counts) {
  __shared__ int h[NEXP];
  int tid = threadIdx.x;
  if (tid < NEXP) h[tid] = 0;
  __syncthreads();
  int i = blockIdx.x * 256 + tid;
  atomicAdd(&h[tok_e[i]], 1);
  __syncthreads();
  if (tid < NEXP && h[tid] > 0) atomicAdd(&counts[tid], h[tid]);
}

__global__ void scan_build_kernel(const int* __restrict__ counts, int* __restrict__ basep,
                                  int* __restrict__ tileA_e, int* __restrict__ tileA_mt,
                                  int* __restrict__ ntiles) {
  if (threadIdx.x != 0 || blockIdx.x != 0) return;
  int s = 0;
  for (int e = 0; e < NEXP; ++e) { basep[e] = s; s += counts[e]; }
  int na = 0;
  for (int e = 0; e < NEXP; ++e) {
    int nmt = (counts[e] + 127) >> 7;
    for (int m = 0; m < nmt; ++m) { tileA_e[na] = e; tileA_mt[na] = m; ++na; }
  }
  ntiles[1] = na;
}

__global__ __launch_bounds__(256) void scatter_kernel(const int* __restrict__ tok_e,
                                                      const float* __restrict__ tok_w,
                                                      const int* __restrict__ base,
                                                      int* __restrict__ cursor,
                                                      int* __restrict__ pair_tok,
                                                      float* __restrict__ pair_w) {
  __shared__ int h[NEXP], bstart[NEXP];
  int tid = threadIdx.x;
  if (tid < NEXP) h[tid] = 0;
  __syncthreads();
  int i = blockIdx.x * 256 + tid;
  int e = tok_e[i];
  int r = atomicAdd(&h[e], 1);
  __syncthreads();
  if (tid < NEXP) bstart[tid] = (h[tid] > 0) ? atomicAdd(&cursor[tid], h[tid]) : 0;
  __syncthreads();
  int pos = base[e] + bstart[e] + r;
  pair_tok[pos] = i;          // packed (tok<<1)|slot
  pair_w[pos] = tok_w[i];
}

// ================= grouped GEMM: 128x128 tile, BK=64, 4 waves, 3 blocks/CU =================
// MODE 0: H = gelu(X * Wi^T + bi) -> hbuf (bf16). A gathered via pair_tok, K=768,  NT=12
// MODE 1: stage = (H * Wo^T + bo) * w  (f32).   A contiguous (hbuf),     K=3072, NT=48
// acc[4][4] = 64 AGPR/wave; ~148 total regs <= 512/3 -> 3 waves/SIMD -> 3 blocks/CU.
// (R12 proved co-resident blocks 2x the staging feed; this pushes 2->3.)
// Single 32 KB LDS buffer; loop: reads -> lgkm0 -> bar -> stage(t+1) -> MFMA -> vmcnt0 -> bar.
template <int MODE>
__global__ __launch_bounds__(256, 3) void moe_gemm128(
    const unsigned short* __restrict__ abase,
    const unsigned short* __restrict__ wbase,
    const float* __restrict__ bias,
    const int* __restrict__ counts, const int* __restrict__ base,
    const int* __restrict__ pair_tok, const float* __restrict__ pair_w,
    const int* __restrict__ tileA_e, const int* __restrict__ tileA_mt,
    const int* __restrict__ ntiles,
    unsigned short* __restrict__ hbuf, float* __restrict__ stage) {
  constexpr int K  = MODE ? FDIM : HDIM;
  constexpr int N  = MODE ? HDIM : FDIM;
  constexpr int NT = K / 64;

  // decode: xcd = bid&7, slot = bid>>3; nt-major / mt-inner (18 mt slots per XCD)
  const int xcd = blockIdx.x & 7;
  const int slot = blockIdx.x >> 3;
  const int mtl = slot % 18;
  const int nt = slot / 18;
  const int ntl = ntiles[1];
  const int q = ntl >> 3, r = ntl & 7;
  const int cnt = q + (xcd < r ? 1 : 0);
  if (mtl >= cnt) return;
  const int gt = xcd * q + (xcd < r ? xcd : r) + mtl;
  const int e = tileA_e[gt];
  const int mt = tileA_mt[gt];
  const int ne = counts[e];
  const int pb = base[e];

  extern __shared__ char smem[];      // A 16KB @0 | B 16KB @16384

  const int tid = threadIdx.x;        // 0..255
  const int lane = tid & 63;
  const int wv = tid >> 6;            // 4 waves
  const int wm = wv >> 1;             // 0..1 (64-row half)
  const int wn = wv & 1;              // 0..1 (64-col half)
  const int l15 = lane & 15;
  const int lkb = (lane >> 4) * 16;

  // staging: 256 thr x 16B = 4 KB/call; chunk c covers 32 rows
  const int crow = tid >> 3;          // 0..31
  const int ck = tid & 7;
  const int swz = (ck ^ (crow & 7)) * 16;
  const char* aS[4]; const char* bS[4];
#pragma unroll
  for (int c = 0; c < 4; ++c) {
    int gr = mt * 128 + c * 32 + crow; if (gr > ne - 1) gr = ne - 1;
    if constexpr (MODE == 0) {
      int tok = pair_tok[pb + gr] >> 1;
      aS[c] = (const char*)abase + (size_t)tok * (HDIM * 2) + swz;
    } else {
      aS[c] = (const char*)abase + (size_t)(pb + gr) * (FDIM * 2) + swz;
    }
    int br = nt * 128 + c * 32 + crow;
    bS[c] = (const char*)wbase + ((size_t)e * N * K + (size_t)br * K) * 2 + swz;
  }

  auto STAGE = [&](int t) {
    if (t < NT) {
#pragma unroll
      for (int c = 0; c < 4; ++c) {
        __builtin_amdgcn_global_load_lds(
            (const __attribute__((address_space(1))) void*)(aS[c] + t * 128),
            (__attribute__((address_space(3))) void*)(smem + c * 4096 + tid * 16), 16, 0, 0);
        __builtin_amdgcn_global_load_lds(
            (const __attribute__((address_space(1))) void*)(bS[c] + t * 128),
            (__attribute__((address_space(3))) void*)(smem + 16384 + c * 4096 + tid * 16),
            16, 0, 0);
      }
    }
  };

  f32x4 acc[4][4];
#pragma unroll
  for (int mf = 0; mf < 4; ++mf)
#pragma unroll
    for (int nf = 0; nf < 4; ++nf) acc[mf][nf] = (f32x4){0.f, 0.f, 0.f, 0.f};

  STAGE(0);
  asm volatile("s_waitcnt vmcnt(0)" ::: "memory");
  __builtin_amdgcn_s_barrier();

  for (int t = 0; t < NT; ++t) {
    bf16x8 aF[8], bF[8];
#pragma unroll
    for (int mf = 0; mf < 4; ++mf)
#pragma unroll
      for (int kh = 0; kh < 2; ++kh) {
        int lr = wm * 64 + mf * 16 + l15;
        aF[mf * 2 + kh] =
            *(const bf16x8*)(smem + lr * 128 + ((kh * 64 + lkb) ^ ((lr & 7) << 4)));
      }
#pragma unroll
    for (int nf = 0; nf < 4; ++nf)
#pragma unroll
      for (int kh = 0; kh < 2; ++kh) {
        int lb = wn * 64 + nf * 16 + l15;
        bF[nf * 2 + kh] =
            *(const bf16x8*)(smem + 16384 + lb * 128 + ((kh * 64 + lkb) ^ ((lb & 7) << 4)));
      }
    asm volatile("s_waitcnt lgkmcnt(0)" ::: "memory");
    __builtin_amdgcn_sched_barrier(0);
    __builtin_amdgcn_s_barrier();             // all reads retired -> buffer free
    STAGE(t + 1);                             // next tile into same buffer
    __builtin_amdgcn_sched_barrier(0);
    __builtin_amdgcn_s_setprio(1);
#pragma unroll
    for (int mf = 0; mf < 4; ++mf)
#pragma unroll
      for (int nf = 0; nf < 4; ++nf)
#pragma unroll
        for (int kh = 0; kh < 2; ++kh)
          acc[mf][nf] = mfma16(aF[mf * 2 + kh], bF[nf * 2 + kh], acc[mf][nf]);
    __builtin_amdgcn_s_setprio(0);
    __builtin_amdgcn_sched_barrier(0);
    asm volatile("s_waitcnt vmcnt(0)" ::: "memory");
    __builtin_amdgcn_s_barrier();
  }

  // epilogue: row = mt*128 + wm*64 + mf*16 + (lane>>4)*4 + rr; col = nt*128 + wn*64 + nf*16 + l15
  if constexpr (MODE == 0) {
    const float* be = bias + (size_t)e * FDIM;
    float bv[4];
#pragma unroll
    for (int nf = 0; nf < 4; ++nf) bv[nf] = be[nt * 128 + wn * 64 + nf * 16 + l15];
#pragma unroll
    for (int mf = 0; mf < 4; ++mf)
#pragma unroll
      for (int rr = 0; rr < 4; ++rr) {
        int row = mt * 128 + wm * 64 + mf * 16 + (lane >> 4) * 4 + rr;
        if (row < ne) {
          unsigned short* hr = hbuf + (size_t)(pb + row) * FDIM + nt * 128 + wn * 64 + l15;
#pragma unroll
          for (int nf = 0; nf < 4; ++nf)
            hr[nf * 16] = f2b(gelu_f(acc[mf][nf][rr] + bv[nf]));
        }
      }
  } else {
    const float* be = bias + (size_t)e * HDIM;
    float bv[4];
#pragma unroll
    for (int nf = 0; nf < 4; ++nf) bv[nf] = be[nt * 128 + wn * 64 + nf * 16 + l15];
#pragma unroll
    for (int mf = 0; mf < 4; ++mf)
#pragma unroll
      for (int rr = 0; rr < 4; ++rr) {
        int row = mt * 128 + wm * 64 + mf * 16 + (lane >> 4) * 4 + rr;
        if (row < ne) {
          int p = pb + row;
          int ts = pair_tok[p];        // (tok<<1)|slot in [0,16384)
          float w = pair_w[p];
          float* sr = stage + (size_t)ts * HDIM + nt * 128 + wn * 64 + l15;
#pragma unroll
          for (int nf = 0; nf < 4; ++nf)
            sr[nf * 16] = (acc[mf][nf][rr] + bv[nf]) * w;
        }
      }
  }
}

// ---------------- combine: out[t] = stage[2t] + stage[2t+1] ----------------
__global__ __launch_bounds__(256) void combine_kernel(const float* __restrict__ stage,
                                                      float* __restrict__ out) {
  const int n4 = T_TOK * HDIM / 4;
  int i = blockIdx.x * 256 + threadIdx.x;
  int stride = gridDim.x * 256;
  const float4* s = (const float4*)stage;
  float4* o = (float4*)out;
  for (; i < n4; i += stride) {
    int t = i / (HDIM / 4);
    int h = i - t * (HDIM / 4);
    float4 a = s[(size_t)t * (HDIM / 2) + h];
    float4 b = s[(size_t)t * (HDIM / 2) + (HDIM / 4) + h];
    float4 rr; rr.x = a.x + b.x; rr.y = a.y + b.y; rr.z = a.z + b.z; rr.w = a.w + b.w;
    o[i] = rr;
  }
}

extern "C" void kernel_launch(void* const* d_in, const int* in_sizes, int n_in,
                              void* d_out, int out_size, void* d_ws, size_t ws_size,
                              hipStream_t stream) {
  const float* x  = (const float*)d_in[0];
  const float* Wr = (const float*)d_in[1];
  const float* Wi = (const float*)d_in[2];
  const float* bi = (const float*)d_in[3];
  const float* Wo = (const float*)d_in[4];
  const float* bo = (const float*)d_in[5];
  float* out = (float*)d_out;
  char* ws = (char*)d_ws;

  unsigned short* xb   = (unsigned short*)(ws + OFF_XB);
  unsigned short* wib  = (unsigned short*)(ws + OFF_WIB);
  unsigned short* wob  = (unsigned short*)(ws + OFF_WOB);
  unsigned short* hbuf = (unsigned short*)(ws + OFF_HBUF);
  int*   counts   = (int*)(ws + OFF_META);
  int*   basep    = (int*)(ws + OFF_META + 64);
  int*   cursor   = (int*)(ws + OFF_META + 128);
  int*   tok_e    = (int*)(ws + OFF_TOKE);
  float* tok_w    = (float*)(ws + OFF_TOKW);
  int*   pair_tok = (int*)(ws + OFF_PTOK);
  float* pair_w   = (float*)(ws + OFF_PW);
  int*   tileA_e  = (int*)(ws + OFF_TILE);
  int*   tileA_mt = (int*)(ws + OFF_TILE + 1024);
  int*   ntiles   = (int*)(ws + OFF_TILE + 2048);
  float* stage    = (float*)(ws + OFF_STAGE);

  hipFuncSetAttribute((const void*)&moe_gemm128<0>,
                      hipFuncAttributeMaxDynamicSharedMemorySize, 32768);
  hipFuncSetAttribute((const void*)&moe_gemm128<1>,
                      hipFuncAttributeMaxDynamicSharedMemorySize, 32768);

  hipMemsetAsync(ws + OFF_META, 0, 256, stream);

  router_kernel<<<T_TOK / 4, 256, 0, stream>>>(x, Wr, tok_e, tok_w, xb);
  cvt_kernel<<<2048, 256, 0, stream>>>(Wi, wib, NEXP * FDIM * HDIM / 4);
  cvt_kernel<<<2048, 256, 0, stream>>>(Wo, wob, NEXP * HDIM * FDIM / 4);

  count_kernel<<<64, 256, 0, stream>>>(tok_e, counts);
  scan_build_kernel<<<1, 64, 0, stream>>>(counts, basep, tileA_e, tileA_mt, ntiles);
  scatter_kernel<<<64, 256, 0, stream>>>(tok_e, tok_w, basep, cursor, pair_tok, pair_w);

  // gemmA: 8 XCDs x 18 mt-slots x 24 nt; 3 blocks/CU (32 KB LDS, 4 waves, 148 regs)
  moe_gemm128<0><<<8 * 18 * (FDIM / 128), 256, 32768, stream>>>(
      xb, wib, bi, counts, basep, pair_tok, pair_w, tileA_e, tileA_mt, ntiles, hbuf, nullptr);
  // gemmB: 8 XCDs x 18 mt-slots x 6 nt; same structure, K=3072
  moe_gemm128<1><<<8 * 18 * (HDIM / 128), 256, 32768, stream>>>(
      hbuf, wob, bo, counts, basep, pair_tok, pair_w, tileA_e, tileA_mt, ntiles, nullptr, stage);

  combine_kernel<<<2048, 256, 0, stream>>>(stage, out);
}

// Round 14
// 292.735 us; speedup vs baseline: 1.0361x; 1.0361x over previous
//
#include <hip/hip_runtime.h>
#include <hip/hip_bf16.h>
#include <cstdint>
#include <cstddef>

// BertMoE: B=4,S=2048,H=768,F=3072,E=8,K=2. tokens T=8192, pairs=16384.
#define T_TOK 8192
#define HDIM  768
#define FDIM  3072
#define NEXP  8

typedef __attribute__((ext_vector_type(8))) __bf16 bf16x8;
typedef __attribute__((ext_vector_type(4))) float  f32x4;

static __device__ __forceinline__ f32x4 mfma16(bf16x8 a, bf16x8 b, f32x4 c) {
  return __builtin_amdgcn_mfma_f32_16x16x32_bf16(a, b, c, 0, 0, 0);
}

static __device__ __forceinline__ unsigned short f2b(float f) {
  return __builtin_bit_cast(unsigned short, (__bf16)f);
}

// fast gelu: 0.5x(1+tanh(0.79788456(x+0.044715x^3))), max |err| ~3e-4 (R5/R6-validated)
static __device__ __forceinline__ float gelu_f(float x) {
  float x2 = x * x;
  float y = x * (0.7978845608f + 0.0356774081f * x2);
  float ay = __builtin_fabsf(y);
  float z = __builtin_amdgcn_exp2f(ay * -2.885390082f);   // exp(-2|y|)
  float t = (1.0f - z) * __builtin_amdgcn_rcpf(1.0f + z);
  t = __builtin_copysignf(t, y);
  return 0.5f * x * (1.0f + t);
}

// ---------------- workspace layout (bytes) ----------------
static constexpr size_t OFF_XB   = 0;                                        // T*H bf16
static constexpr size_t OFF_WIB  = OFF_XB  + (size_t)T_TOK * HDIM * 2;       // E*F*H bf16
static constexpr size_t OFF_WOB  = OFF_WIB + (size_t)NEXP * FDIM * HDIM * 2; // E*H*F bf16
static constexpr size_t OFF_HBUF = OFF_WOB + (size_t)NEXP * HDIM * FDIM * 2; // 2T*F bf16
static constexpr size_t OFF_META = OFF_HBUF + (size_t)2 * T_TOK * FDIM * 2;
static constexpr size_t OFF_TOKE = OFF_META + 256;
static constexpr size_t OFF_TOKW = OFF_TOKE + 65536;
static constexpr size_t OFF_PTOK = OFF_TOKW + 65536;
static constexpr size_t OFF_PW   = OFF_PTOK + 65536;
static constexpr size_t OFF_TILE = OFF_PW + 65536;
// OFF_TILE layout: tileA_e[256] | tileA_mt[256] | ntiles[2]  (128-row tiles)
// stage [16384][768] f32 = 50.33 MB: ALIASES xb+wib (dead once gemmA is done)
static constexpr size_t OFF_STAGE = 0;

// ---------------- fp32 -> bf16 convert ----------------
__global__ __launch_bounds__(256) void cvt_kernel(const float* __restrict__ s,
                                                  unsigned short* __restrict__ d, int n4) {
  int i = blockIdx.x * 256 + threadIdx.x;
  int stride = gridDim.x * 256;
  for (; i < n4; i += stride) {
    float4 v = ((const float4*)s)[i];
    ushort4 o;
    o.x = f2b(v.x); o.y = f2b(v.y); o.z = f2b(v.z); o.w = f2b(v.w);
    ((ushort4*)d)[i] = o;
  }
}

// ---------------- router: logits, top2, softmax; also emits xb (bf16 of x) ----------------
__global__ __launch_bounds__(256) void router_kernel(const float* __restrict__ x,
                                                     const float* __restrict__ Wr,
                                                     int* __restrict__ tok_e,
                                                     float* __restrict__ tok_w,
                                                     unsigned short* __restrict__ xb) {
  __shared__ float wr[NEXP * HDIM];
  int tid = threadIdx.x;
  for (int i = tid; i < NEXP * HDIM; i += 256) wr[i] = Wr[i];
  __syncthreads();
  int lane = tid & 63;
  int wv = tid >> 6;
  int t = blockIdx.x * 4 + wv;
  const float* xr = x + (size_t)t * HDIM;
  unsigned short* xbr = xb + (size_t)t * HDIM;
  float p[NEXP];
#pragma unroll
  for (int e = 0; e < NEXP; ++e) p[e] = 0.f;
  for (int j = 0; j < HDIM / 64; ++j) {
    float xv = xr[j * 64 + lane];
    xbr[j * 64 + lane] = f2b(xv);
#pragma unroll
    for (int e = 0; e < NEXP; ++e) p[e] += xv * wr[e * HDIM + j * 64 + lane];
  }
#pragma unroll
  for (int e = 0; e < NEXP; ++e) {
    float v = p[e];
    for (int off = 32; off; off >>= 1) v += __shfl_xor(v, off);
    p[e] = v;
  }
  if (lane == 0) {
    float v0 = -1e30f, v1 = -1e30f; int i0 = 0, i1 = 0;
#pragma unroll
    for (int e = 0; e < NEXP; ++e) {
      float v = p[e];
      if (v > v0) { v1 = v0; i1 = i0; v0 = v; i0 = e; }
      else if (v > v1) { v1 = v; i1 = e; }
    }
    float ew = expf(v1 - v0);
    float w0 = 1.0f / (1.0f + ew);
    float w1 = ew * w0;
    tok_e[t * 2 + 0] = i0; tok_w[t * 2 + 0] = w0;
    tok_e[t * 2 + 1] = i1; tok_w[t * 2 + 1] = w1;
  }
}

// ---------------- count / scan+tiles / scatter ----------------
__global__ __launch_bounds__(256) void count_kernel(const int* __restrict__ tok_e,
                                                    int* __restrict__ counts) {
  __shared__ int h[NEXP];
  int tid = threadIdx.x;
  if (tid < NEXP) h[tid] = 0;
  __syncthreads();
  int i = blockIdx.x * 256 + tid;
  atomicAdd(&h[tok_e[i]], 1);
  __syncthreads();
  if (tid < NEXP && h[tid] > 0) atomicAdd(&counts[tid], h[tid]);
}

__global__ void scan_build_kernel(const int* __restrict__ counts, int* __restrict__ basep,
                                  int* __restrict__ tileA_e, int* __restrict__ tileA_mt,
                                  int* __restrict__ ntiles) {
  if (threadIdx.x != 0 || blockIdx.x != 0) return;
  int s = 0;
  for (int e = 0; e < NEXP; ++e) { basep[e] = s; s += counts[e]; }
  int na = 0;
  for (int e = 0; e < NEXP; ++e) {
    int nmt = (counts[e] + 127) >> 7;
    for (int m = 0; m < nmt; ++m) { tileA_e[na] = e; tileA_mt[na] = m; ++na; }
  }
  ntiles[1] = na;
}

__global__ __launch_bounds__(256) void scatter_kernel(const int* __restrict__ tok_e,
                                                      const float* __restrict__ tok_w,
                                                      const int* __restrict__ base,
                                                      int* __restrict__ cursor,
                                                      int* __restrict__ pair_tok,
                                                      float* __restrict__ pair_w) {
  __shared__ int h[NEXP], bstart[NEXP];
  int tid = threadIdx.x;
  if (tid < NEXP) h[tid] = 0;
  __syncthreads();
  int i = blockIdx.x * 256 + tid;
  int e = tok_e[i];
  int r = atomicAdd(&h[e], 1);
  __syncthreads();
  if (tid < NEXP) bstart[tid] = (h[tid] > 0) ? atomicAdd(&cursor[tid], h[tid]) : 0;
  __syncthreads();
  int pos = base[e] + bstart[e] + r;
  pair_tok[pos] = i;          // packed (tok<<1)|slot
  pair_w[pos] = tok_w[i];
}

// ========== grouped GEMM: 128x256 tile, BK=64, 4 waves (wave 128x64), 2 blocks/CU ==========
// MODE 0: H = gelu(X * Wi^T + bi) -> hbuf (bf16). A gathered via pair_tok, K=768,  NT=12, nt=12
// MODE 1: stage = (H * Wo^T + bo) * w  (f32).   A contiguous (hbuf),     K=3072, NT=48, nt=3
// bytes/FLOP = 0.75x of the 128^2 tile at the SAME 2-blocks/CU concurrency (the reg quantum
// 129-256 gives 2 waves/SIMD regardless, so acc can be 128 AGPR for free).
// kh-split loop keeps peak frag regs at 48 VGPR: readsK0 -> MFMA K0 -> readsK1 -> bar ->
// STAGE(t+1) -> MFMA K1 -> vmcnt0 -> bar.  LDS 48 KB (A 16K | B 32K), single-buffered.
template <int MODE>
__global__ __launch_bounds__(256, 2) void moe_gemm128(
    const unsigned short* __restrict__ abase,
    const unsigned short* __restrict__ wbase,
    const float* __restrict__ bias,
    const int* __restrict__ counts, const int* __restrict__ base,
    const int* __restrict__ pair_tok, const float* __restrict__ pair_w,
    const int* __restrict__ tileA_e, const int* __restrict__ tileA_mt,
    const int* __restrict__ ntiles,
    unsigned short* __restrict__ hbuf, float* __restrict__ stage) {
  constexpr int K  = MODE ? FDIM : HDIM;
  constexpr int N  = MODE ? HDIM : FDIM;
  constexpr int NT = K / 64;

  // decode: xcd = bid&7, slot = bid>>3; nt-major / mt-inner (18 mt slots per XCD)
  const int xcd = blockIdx.x & 7;
  const int slot = blockIdx.x >> 3;
  const int mtl = slot % 18;
  const int nt = slot / 18;
  const int ntl = ntiles[1];
  const int q = ntl >> 3, r = ntl & 7;
  const int cnt = q + (xcd < r ? 1 : 0);
  if (mtl >= cnt) return;
  const int gt = xcd * q + (xcd < r ? xcd : r) + mtl;
  const int e = tileA_e[gt];
  const int mt = tileA_mt[gt];
  const int ne = counts[e];
  const int pb = base[e];

  extern __shared__ char smem[];      // A 16KB @0 | B 32KB @16384

  const int tid = threadIdx.x;        // 0..255
  const int lane = tid & 63;
  const int wn = tid >> 6;            // 4 waves = 4 col bands of 64
  const int l15 = lane & 15;
  const int lkb = (lane >> 4) * 16;

  // staging: chunk = 32 rows x 128B = 4 KB (256 thr x 16B)
  const int crow = tid >> 3;          // 0..31
  const int ck = tid & 7;
  const int swz = (ck ^ (crow & 7)) * 16;
  const char* aS[4];
#pragma unroll
  for (int c = 0; c < 4; ++c) {
    int gr = mt * 128 + c * 32 + crow; if (gr > ne - 1) gr = ne - 1;
    if constexpr (MODE == 0) {
      int tok = pair_tok[pb + gr] >> 1;
      aS[c] = (const char*)abase + (size_t)tok * (HDIM * 2) + swz;
    } else {
      aS[c] = (const char*)abase + (size_t)(pb + gr) * (FDIM * 2) + swz;
    }
  }
  const char* bS = (const char*)wbase +
                   ((size_t)e * N * K + (size_t)(nt * 256 + crow) * K) * 2 + swz;

  auto STAGE = [&](int t) {
    if (t < NT) {
#pragma unroll
      for (int c = 0; c < 4; ++c)
        __builtin_amdgcn_global_load_lds(
            (const __attribute__((address_space(1))) void*)(aS[c] + t * 128),
            (__attribute__((address_space(3))) void*)(smem + c * 4096 + tid * 16), 16, 0, 0);
#pragma unroll
      for (int c = 0; c < 8; ++c)
        __builtin_amdgcn_global_load_lds(
            (const __attribute__((address_space(1))) void*)(bS + (size_t)c * (32 * K * 2) + t * 128),
            (__attribute__((address_space(3))) void*)(smem + 16384 + c * 4096 + tid * 16),
            16, 0, 0);
    }
  };

  f32x4 acc[8][4];                    // 128 AGPR: wave tile 128 rows x 64 cols
#pragma unroll
  for (int mf = 0; mf < 8; ++mf)
#pragma unroll
    for (int nf = 0; nf < 4; ++nf) acc[mf][nf] = (f32x4){0.f, 0.f, 0.f, 0.f};

  auto RD = [&](int kh, bf16x8* aF, bf16x8* bF) {
#pragma unroll
    for (int mf = 0; mf < 8; ++mf) {
      int lr = mf * 16 + l15;
      aF[mf] = *(const bf16x8*)(smem + lr * 128 + ((kh * 64 + lkb) ^ ((lr & 7) << 4)));
    }
#pragma unroll
    for (int nf = 0; nf < 4; ++nf) {
      int lb = wn * 64 + nf * 16 + l15;
      bF[nf] = *(const bf16x8*)(smem + 16384 + lb * 128 + ((kh * 64 + lkb) ^ ((lb & 7) << 4)));
    }
  };
  auto MM = [&](const bf16x8* aF, const bf16x8* bF) {
#pragma unroll
    for (int mf = 0; mf < 8; ++mf)
#pragma unroll
      for (int nf = 0; nf < 4; ++nf)
        acc[mf][nf] = mfma16(aF[mf], bF[nf], acc[mf][nf]);
  };

  STAGE(0);
  asm volatile("s_waitcnt vmcnt(0)" ::: "memory");
  __builtin_amdgcn_s_barrier();

  for (int t = 0; t < NT; ++t) {
    bf16x8 aF[8], bF[4];
    // k-half 0: read + MFMA (pure compute, no buffer hazard)
    RD(0, aF, bF);
    asm volatile("s_waitcnt lgkmcnt(0)" ::: "memory");
    __builtin_amdgcn_sched_barrier(0);
    __builtin_amdgcn_s_setprio(1);
    MM(aF, bF);
    __builtin_amdgcn_s_setprio(0);
    // k-half 1: read, then buffer is free
    RD(1, aF, bF);
    asm volatile("s_waitcnt lgkmcnt(0)" ::: "memory");
    __builtin_amdgcn_sched_barrier(0);
    __builtin_amdgcn_s_barrier();     // all waves' reads retired -> buffer free
    STAGE(t + 1);                     // issue next tile into same buffer
    __builtin_amdgcn_sched_barrier(0);
    __builtin_amdgcn_s_setprio(1);
    MM(aF, bF);                       // overlaps the staging loads
    __builtin_amdgcn_s_setprio(0);
    __builtin_amdgcn_sched_barrier(0);
    asm volatile("s_waitcnt vmcnt(0)" ::: "memory");
    __builtin_amdgcn_s_barrier();
  }

  // epilogue: row = mt*128 + mf*16 + (lane>>4)*4 + rr; col = nt*256 + wn*64 + nf*16 + l15
  if constexpr (MODE == 0) {
    const float* be = bias + (size_t)e * FDIM;
    float bv[4];
#pragma unroll
    for (int nf = 0; nf < 4; ++nf) bv[nf] = be[nt * 256 + wn * 64 + nf * 16 + l15];
#pragma unroll
    for (int mf = 0; mf < 8; ++mf)
#pragma unroll
      for (int rr = 0; rr < 4; ++rr) {
        int row = mt * 128 + mf * 16 + (lane >> 4) * 4 + rr;
        if (row < ne) {
          unsigned short* hr = hbuf + (size_t)(pb + row) * FDIM + nt * 256 + wn * 64 + l15;
#pragma unroll
          for (int nf = 0; nf < 4; ++nf)
            hr[nf * 16] = f2b(gelu_f(acc[mf][nf][rr] + bv[nf]));
        }
      }
  } else {
    const float* be = bias + (size_t)e * HDIM;
    float bv[4];
#pragma unroll
    for (int nf = 0; nf < 4; ++nf) bv[nf] = be[nt * 256 + wn * 64 + nf * 16 + l15];
#pragma unroll
    for (int mf = 0; mf < 8; ++mf)
#pragma unroll
      for (int rr = 0; rr < 4; ++rr) {
        int row = mt * 128 + mf * 16 + (lane >> 4) * 4 + rr;
        if (row < ne) {
          int p = pb + row;
          int ts = pair_tok[p];        // (tok<<1)|slot in [0,16384)
          float w = pair_w[p];
          float* sr = stage + (size_t)ts * HDIM + nt * 256 + wn * 64 + l15;
#pragma unroll
          for (int nf = 0; nf < 4; ++nf)
            sr[nf * 16] = (acc[mf][nf][rr] + bv[nf]) * w;
        }
      }
  }
}

// ---------------- combine: out[t] = stage[2t] + stage[2t+1] ----------------
__global__ __launch_bounds__(256) void combine_kernel(const float* __restrict__ stage,
                                                      float* __restrict__ out) {
  const int n4 = T_TOK * HDIM / 4;
  int i = blockIdx.x * 256 + threadIdx.x;
  int stride = gridDim.x * 256;
  const float4* s = (const float4*)stage;
  float4* o = (float4*)out;
  for (; i < n4; i += stride) {
    int t = i / (HDIM / 4);
    int h = i - t * (HDIM / 4);
    float4 a = s[(size_t)t * (HDIM / 2) + h];
    float4 b = s[(size_t)t * (HDIM / 2) + (HDIM / 4) + h];
    float4 rr; rr.x = a.x + b.x; rr.y = a.y + b.y; rr.z = a.z + b.z; rr.w = a.w + b.w;
    o[i] = rr;
  }
}

extern "C" void kernel_launch(void* const* d_in, const int* in_sizes, int n_in,
                              void* d_out, int out_size, void* d_ws, size_t ws_size,
                              hipStream_t stream) {
  const float* x  = (const float*)d_in[0];
  const float* Wr = (const float*)d_in[1];
  const float* Wi = (const float*)d_in[2];
  const float* bi = (const float*)d_in[3];
  const float* Wo = (const float*)d_in[4];
  const float* bo = (const float*)d_in[5];
  float* out = (float*)d_out;
  char* ws = (char*)d_ws;

  unsigned short* xb   = (unsigned short*)(ws + OFF_XB);
  unsigned short* wib  = (unsigned short*)(ws + OFF_WIB);
  unsigned short* wob  = (unsigned short*)(ws + OFF_WOB);
  unsigned short* hbuf = (unsigned short*)(ws + OFF_HBUF);
  int*   counts   = (int*)(ws + OFF_META);
  int*   basep    = (int*)(ws + OFF_META + 64);
  int*   cursor   = (int*)(ws + OFF_META + 128);
  int*   tok_e    = (int*)(ws + OFF_TOKE);
  float* tok_w    = (float*)(ws + OFF_TOKW);
  int*   pair_tok = (int*)(ws + OFF_PTOK);
  float* pair_w   = (float*)(ws + OFF_PW);
  int*   tileA_e  = (int*)(ws + OFF_TILE);
  int*   tileA_mt = (int*)(ws + OFF_TILE + 1024);
  int*   ntiles   = (int*)(ws + OFF_TILE + 2048);
  float* stage    = (float*)(ws + OFF_STAGE);

  hipFuncSetAttribute((const void*)&moe_gemm128<0>,
                      hipFuncAttributeMaxDynamicSharedMemorySize, 49152);
  hipFuncSetAttribute((const void*)&moe_gemm128<1>,
                      hipFuncAttributeMaxDynamicSharedMemorySize, 49152);

  hipMemsetAsync(ws + OFF_META, 0, 256, stream);

  router_kernel<<<T_TOK / 4, 256, 0, stream>>>(x, Wr, tok_e, tok_w, xb);
  cvt_kernel<<<2048, 256, 0, stream>>>(Wi, wib, NEXP * FDIM * HDIM / 4);
  cvt_kernel<<<2048, 256, 0, stream>>>(Wo, wob, NEXP * HDIM * FDIM / 4);

  count_kernel<<<64, 256, 0, stream>>>(tok_e, counts);
  scan_build_kernel<<<1, 64, 0, stream>>>(counts, basep, tileA_e, tileA_mt, ntiles);
  scatter_kernel<<<64, 256, 0, stream>>>(tok_e, tok_w, basep, cursor, pair_tok, pair_w);

  // gemmA: 8 XCDs x 18 mt-slots x 12 nt (BN=256); 2 blocks/CU (48 KB LDS, 4 waves)
  moe_gemm128<0><<<8 * 18 * (FDIM / 256), 256, 49152, stream>>>(
      xb, wib, bi, counts, basep, pair_tok, pair_w, tileA_e, tileA_mt, ntiles, hbuf, nullptr);
  // gemmB: 8 XCDs x 18 mt-slots x 3 nt; same structure, K=3072
  moe_gemm128<1><<<8 * 18 * (HDIM / 256), 256, 49152, stream>>>(
      hbuf, wob, bo, counts, basep, pair_tok, pair_w, tileA_e, tileA_mt, ntiles, nullptr, stage);

  combine_kernel<<<2048, 256, 0, stream>>>(stage, out);
}